// Round 1
// baseline (1204.579 us; speedup 1.0000x reference)
//
#include <hip/hip_runtime.h>
#include <hip/hip_bf16.h>

typedef unsigned short u16;
typedef unsigned int u32;
typedef unsigned long long u64;

// Problem constants: B=8, S=4096, D=1024, F=2048, E=8, K=2
constexpr int D_ = 1024, F_ = 2048, E_ = 8, K_ = 2;
constexpr int T_ = 8 * 4096;               // 32768 tokens
constexpr int PAIRS = T_ * K_;             // 65536 (token, k) pairs
constexpr int MAXROWS = PAIRS + E_ * 128;  // worst-case padded rows = 66560
constexpr int MAXTILES = MAXROWS / 128;    // 520

// ws layout (all offsets multiples of 1024)
constexpr size_t OFF_HDR  = 0;                                  // 64 ints
constexpr size_t OFF_ZP   = 1024;                               // 2048 B zero page
constexpr size_t OFF_PERM = 4096;                               // MAXROWS i32
constexpr size_t OFF_GATE = OFF_PERM + (size_t)MAXROWS * 4;     // MAXROWS f32
constexpr size_t OFF_XB   = OFF_GATE + (size_t)MAXROWS * 4;     // x as bf16
constexpr size_t OFF_W1B  = OFF_XB  + (size_t)T_ * D_ * 2;      // w1 bf16
constexpr size_t OFF_W2B  = OFF_W1B + (size_t)E_ * F_ * D_ * 2; // w2 bf16
constexpr size_t OFF_H    = OFF_W2B + (size_t)E_ * D_ * F_ * 2; // h bf16 (gate*silu)
constexpr size_t WS_NEED  = OFF_H + (size_t)MAXROWS * F_ * 2;   // ~407 MB

// header: [0..7] counts, [8..15] cursor, [16..24] row_off, [25..33] tile_off, [34] total_tiles

__device__ __forceinline__ u16 f2b(float f) {
  union { __hip_bfloat16 b; u16 u; } cv; cv.b = __float2bfloat16(f); return cv.u;
}

// ---------------- init: zero out, default routing arrays, zero page ----------------
__global__ void k_init(float4* out4, int* hdr, int* perm, float* gates, float4* zp4) {
  int i = blockIdx.x * blockDim.x + threadIdx.x;   // exactly 8388608 threads
  out4[i] = float4{0.f, 0.f, 0.f, 0.f};
  if (i < MAXROWS) { perm[i] = -1; gates[i] = 0.f; }
  if (i < 64) hdr[i] = 0;
  if (i < 128) zp4[i] = float4{0.f, 0.f, 0.f, 0.f};
}

// ---------------- fp32 -> bf16 conversion of x, w1, w2 ----------------
__global__ void k_convert(const float4* __restrict__ x, const float4* __restrict__ w1,
                          const float4* __restrict__ w2, ushort4* __restrict__ xb,
                          ushort4* __restrict__ w1b, ushort4* __restrict__ w2b) {
  int i = blockIdx.x * blockDim.x + threadIdx.x;   // exactly 16777216 threads
  float4 v; ushort4* dst; int o;
  if (i < 8388608)       { o = i;            v = x[o];  dst = xb;  }
  else if (i < 12582912) { o = i - 8388608;  v = w1[o]; dst = w1b; }
  else                   { o = i - 12582912; v = w2[o]; dst = w2b; }
  ushort4 r; r.x = f2b(v.x); r.y = f2b(v.y); r.z = f2b(v.z); r.w = f2b(v.w);
  dst[o] = r;
}

// ---------------- histogram of expert assignments ----------------
__global__ void k_hist(const int* __restrict__ eidx, int* hdr) {
  __shared__ int lh[E_];
  if (threadIdx.x < E_) lh[threadIdx.x] = 0;
  __syncthreads();
  for (int i = blockIdx.x * blockDim.x + threadIdx.x; i < PAIRS; i += gridDim.x * blockDim.x)
    atomicAdd(&lh[eidx[i]], 1);
  __syncthreads();
  if (threadIdx.x < E_) atomicAdd(&hdr[threadIdx.x], lh[threadIdx.x]);
}

// ---------------- scan: padded row offsets + tile offsets ----------------
__global__ void k_scan(int* hdr) {
  int ro = 0, to = 0;
  hdr[16] = 0; hdr[25] = 0;
  for (int e = 0; e < E_; e++) {
    int c = hdr[e];
    int pad = ((c + 127) / 128) * 128;
    ro += pad; to += pad / 128;
    hdr[17 + e] = ro; hdr[26 + e] = to;
  }
  hdr[34] = to;
}

// ---------------- scatter pairs into per-expert segments (wave-aggregated atomics) --
__global__ void k_scatter(const int* __restrict__ eidx, const float* __restrict__ probs,
                          int* hdr, int* __restrict__ perm, float* __restrict__ gates) {
  int i = blockIdx.x * blockDim.x + threadIdx.x;   // exactly PAIRS threads
  int e = eidx[i];
  float pr = probs[i];
  int tok = i >> 1;  // K=2
  int lane = threadIdx.x & 63;
  u64 lml = (1ull << lane) - 1ull;
  for (int ex = 0; ex < E_; ex++) {
    u64 m = __ballot(e == ex);
    if (m == 0) continue;
    int cnt = __popcll(m);
    int rank = __popcll(m & lml);
    int leader = __builtin_ctzll(m);
    int base = 0;
    if (lane == leader) base = atomicAdd(&hdr[8 + ex], cnt);
    base = __shfl(base, leader, 64);
    if (e == ex) {
      int p = hdr[16 + ex] + base + rank;
      perm[p] = tok;
      gates[p] = pr;
    }
  }
}

// ---------------- MFMA GEMM (m97-style 128x128x64 tile) ----------------
using frag_ab = __attribute__((ext_vector_type(8))) short;  // 8 bf16
using frag_cd = __attribute__((ext_vector_type(4))) float;  // 4 fp32

typedef const __attribute__((address_space(1))) u32* gas_p;
typedef __attribute__((address_space(3))) u32* las_p;

__device__ __forceinline__ void glds16(const void* g, void* l) {
  __builtin_amdgcn_global_load_lds((gas_p)g, (las_p)l, 16, 0, 0);
}

// STAGE 1: h[p, :] = gates[p] * silu(xb[perm[p], :] @ w1b[e]^T)   (M x 2048, K=1024)
// STAGE 2: out[perm[p], :] += h[p, :] @ w2b[e]^T                  (M x 1024, K=2048)
template <int STAGE>
__global__ __launch_bounds__(256, 2) void k_gemm(
    const int* __restrict__ hdr, const int* __restrict__ perm,
    const float* __restrict__ gates, const u16* __restrict__ xb,
    const u16* __restrict__ w1b, const u16* __restrict__ w2b,
    u16* __restrict__ h, float* __restrict__ out, const u16* __restrict__ zp) {
  constexpr int KD = (STAGE == 1) ? 1024 : 2048;  // row length of A and of B (B^T layout)
  constexpr int NT = (STAGE == 1) ? 16 : 8;       // N / 128
  constexpr int KITERS = KD / 64;

  const int mt_blk = blockIdx.x / NT;
  const int nt_blk = blockIdx.x % NT;
  if (mt_blk >= hdr[34]) return;

  // which expert owns this row-tile
  int e = 0;
  while (mt_blk >= hdr[26 + e]) e++;
  const int row0 = hdr[16 + e] + (mt_blk - hdr[25 + e]) * 128;
  const int n0 = nt_blk * 128;

  __shared__ u16 As[128 * 64];
  __shared__ u16 Bs[128 * 64];
  __shared__ u64 rb[128];

  const int tid = threadIdx.x;
  const int w = tid >> 6, lane = tid & 63;
  const int wm = w >> 1, wn = w & 1;
  const int l15 = lane & 15, l4 = lane >> 4;

  if (tid < 128) {
    u64 base;
    if (STAGE == 1) {
      int t = perm[row0 + tid];
      base = (t < 0) ? (u64)zp : (u64)(xb + (size_t)t * D_);
    } else {
      base = (u64)(h + (size_t)(row0 + tid) * F_);
    }
    rb[tid] = base;
  }
  __syncthreads();

  const u16* Bexp = (STAGE == 1) ? (w1b + (size_t)e * F_ * D_) : (w2b + (size_t)e * D_ * F_);

  // staging addresses: wave w stages rows [w*32, w*32+32) of both tiles, 4 instrs each.
  // lane covers row r = w*32 + j*8 + (lane>>3), LDS chunk c = lane&7; fetch global
  // chunk c ^ (r&7) so readers at LDS chunk g^(r&7) see logical chunk g (bank-conflict swizzle).
  const int rsub = lane >> 3;
  const u64 gsw = (u64)(((lane & 7) ^ rsub) * 16);
  u64 arb[4], brb[4];
#pragma unroll
  for (int j = 0; j < 4; j++) {
    int r = w * 32 + j * 8 + rsub;
    arb[j] = rb[r] + gsw;
    brb[j] = (u64)Bexp + (u64)(n0 + r) * (KD * 2) + gsw;
  }

  frag_cd acc[4][4];
#pragma unroll
  for (int i = 0; i < 4; i++)
#pragma unroll
    for (int j = 0; j < 4; j++) acc[i][j] = frag_cd{0.f, 0.f, 0.f, 0.f};

  for (int kit = 0; kit < KITERS; kit++) {
    const u64 koff = (u64)kit * 128;
#pragma unroll
    for (int j = 0; j < 4; j++) {
      glds16((const void*)(arb[j] + koff), (void*)(As + (w * 32 + j * 8) * 64));
      glds16((const void*)(brb[j] + koff), (void*)(Bs + (w * 32 + j * 8) * 64));
    }
    __syncthreads();
#pragma unroll
    for (int kk = 0; kk < 2; kk++) {
      frag_ab af[4], bf[4];
#pragma unroll
      for (int mt = 0; mt < 4; mt++) {
        int r = wm * 64 + mt * 16 + l15;
        int g = kk * 4 + l4;
        af[mt] = *(const frag_ab*)((const char*)As + (size_t)r * 128 + ((g ^ (l15 & 7)) * 16));
      }
#pragma unroll
      for (int nt = 0; nt < 4; nt++) {
        int r = wn * 64 + nt * 16 + l15;
        int g = kk * 4 + l4;
        bf[nt] = *(const frag_ab*)((const char*)Bs + (size_t)r * 128 + ((g ^ (l15 & 7)) * 16));
      }
#pragma unroll
      for (int mt = 0; mt < 4; mt++)
#pragma unroll
        for (int nt = 0; nt < 4; nt++)
          acc[mt][nt] = __builtin_amdgcn_mfma_f32_16x16x32_bf16(af[mt], bf[nt], acc[mt][nt], 0, 0, 0);
    }
    __syncthreads();
  }

  // epilogue. C layout: col = lane&15, row = (lane>>4)*4 + reg  [m89]
  const int col0 = n0 + wn * 64;
  if (STAGE == 1) {
#pragma unroll
    for (int mt = 0; mt < 4; mt++) {
#pragma unroll
      for (int i = 0; i < 4; i++) {
        int p = row0 + wm * 64 + mt * 16 + l4 * 4 + i;
        float gt = gates[p];  // 0 for padded rows
        u16* hrow = h + (size_t)p * F_ + col0;
#pragma unroll
        for (int nt = 0; nt < 4; nt++) {
          float v = acc[mt][nt][i];
          float s = v / (1.f + __expf(-v));  // silu
          hrow[nt * 16 + l15] = f2b(gt * s);
        }
      }
    }
  } else {
#pragma unroll
    for (int mt = 0; mt < 4; mt++) {
#pragma unroll
      for (int i = 0; i < 4; i++) {
        int p = row0 + wm * 64 + mt * 16 + l4 * 4 + i;
        int t = perm[p];
        if (t >= 0) {
          float* orow = out + (size_t)t * D_ + col0;
#pragma unroll
          for (int nt = 0; nt < 4; nt++)
            unsafeAtomicAdd(&orow[nt * 16 + l15], acc[mt][nt][i]);
        }
      }
    }
  }
}

// ---------------- correct-but-slow fallback if ws is too small ----------------
__global__ void k_naive(const float* __restrict__ x, const float* __restrict__ probs,
                        const int* __restrict__ eidx, const float* __restrict__ w1,
                        const float* __restrict__ w2, float* __restrict__ out) {
  __shared__ float xs[D_];
  __shared__ float hs[F_];
  __shared__ float os[D_];
  int t = blockIdx.x, tid = threadIdx.x;
  for (int i = tid; i < D_; i += 256) { xs[i] = x[(size_t)t * D_ + i]; os[i] = 0.f; }
  __syncthreads();
  for (int k = 0; k < K_; k++) {
    int e = eidx[t * K_ + k];
    float g = probs[t * K_ + k];
    const float* W1 = w1 + (size_t)e * F_ * D_;
    for (int f = tid; f < F_; f += 256) {
      const float* wr = W1 + (size_t)f * D_;
      float s = 0.f;
      for (int d = 0; d < D_; d++) s += xs[d] * wr[d];
      hs[f] = s / (1.f + expf(-s));
    }
    __syncthreads();
    const float* W2 = w2 + (size_t)e * D_ * F_;
    for (int dd = tid; dd < D_; dd += 256) {
      const float* wr = W2 + (size_t)dd * F_;
      float s = 0.f;
      for (int f = 0; f < F_; f++) s += hs[f] * wr[f];
      os[dd] += g * s;
    }
    __syncthreads();
  }
  for (int i = tid; i < D_; i += 256) out[(size_t)t * D_ + i] = os[i];
}

extern "C" void kernel_launch(void* const* d_in, const int* in_sizes, int n_in,
                              void* d_out, int out_size, void* d_ws, size_t ws_size,
                              hipStream_t stream) {
  const float* x = (const float*)d_in[0];
  const float* probs = (const float*)d_in[1];
  const int* eidx = (const int*)d_in[2];
  const float* w1 = (const float*)d_in[3];
  const float* w2 = (const float*)d_in[4];
  float* out = (float*)d_out;

  if (ws_size < WS_NEED) {
    k_naive<<<T_, 256, 0, stream>>>(x, probs, eidx, w1, w2, out);
    return;
  }

  char* ws = (char*)d_ws;
  int* hdr = (int*)(ws + OFF_HDR);
  float* zp = (float*)(ws + OFF_ZP);
  int* perm = (int*)(ws + OFF_PERM);
  float* gates = (float*)(ws + OFF_GATE);
  u16* xb = (u16*)(ws + OFF_XB);
  u16* w1b = (u16*)(ws + OFF_W1B);
  u16* w2b = (u16*)(ws + OFF_W2B);
  u16* h = (u16*)(ws + OFF_H);

  k_init<<<32768, 256, 0, stream>>>((float4*)out, hdr, perm, gates, (float4*)zp);
  k_convert<<<65536, 256, 0, stream>>>((const float4*)x, (const float4*)w1, (const float4*)w2,
                                       (ushort4*)xb, (ushort4*)w1b, (ushort4*)w2b);
  k_hist<<<64, 256, 0, stream>>>(eidx, hdr);
  k_scan<<<1, 1, 0, stream>>>(hdr);
  k_scatter<<<PAIRS / 256, 256, 0, stream>>>(eidx, probs, hdr, perm, gates);
  k_gemm<1><<<MAXTILES * 16, 256, 0, stream>>>(hdr, perm, gates, xb, w1b, w2b, h, out, (const u16*)zp);
  k_gemm<2><<<MAXTILES * 8, 256, 0, stream>>>(hdr, perm, gates, xb, w1b, w2b, h, out, (const u16*)zp);
}

// Round 2
// 1179.637 us; speedup vs baseline: 1.0211x; 1.0211x over previous
//
#include <hip/hip_runtime.h>
#include <hip/hip_bf16.h>

typedef unsigned short u16;
typedef unsigned int u32;
typedef unsigned long long u64;

// Problem constants: B=8, S=4096, D=1024, F=2048, E=8, K=2
constexpr int D_ = 1024, F_ = 2048, E_ = 8, K_ = 2;
constexpr int T_ = 8 * 4096;               // 32768 tokens
constexpr int PAIRS = T_ * K_;             // 65536 (token, k) pairs
constexpr int MAXROWS = PAIRS + E_ * 128;  // worst-case padded rows = 66560
constexpr int MAXTILES = MAXROWS / 128;    // 520 (divisible by 8 — XCD swizzle exact)

// ws layout (all offsets multiples of 1024)
constexpr size_t OFF_HDR  = 0;                                  // 64 ints
constexpr size_t OFF_ZP   = 1024;                               // 2048 B zero page
constexpr size_t OFF_PERM = 4096;                               // MAXROWS i32
constexpr size_t OFF_GATE = OFF_PERM + (size_t)MAXROWS * 4;     // MAXROWS f32
constexpr size_t OFF_XB   = OFF_GATE + (size_t)MAXROWS * 4;     // x as bf16
constexpr size_t OFF_W1B  = OFF_XB  + (size_t)T_ * D_ * 2;      // w1 bf16
constexpr size_t OFF_W2B  = OFF_W1B + (size_t)E_ * F_ * D_ * 2; // w2 bf16
constexpr size_t OFF_H    = OFF_W2B + (size_t)E_ * D_ * F_ * 2; // h bf16 (gate*silu)
constexpr size_t WS_NEED  = OFF_H + (size_t)MAXROWS * F_ * 2;   // ~407 MB

// header: [0..7] counts, [8..15] cursor, [16..24] row_off, [25..33] tile_off, [34] total_tiles

__device__ __forceinline__ u16 f2b(float f) {
  union { __hip_bfloat16 b; u16 u; } cv; cv.b = __float2bfloat16(f); return cv.u;
}

// ---------------- init: zero out, default routing arrays, zero page ----------------
__global__ void k_init(float4* out4, int* hdr, int* perm, float* gates, float4* zp4) {
  int i = blockIdx.x * blockDim.x + threadIdx.x;   // exactly 8388608 threads
  out4[i] = float4{0.f, 0.f, 0.f, 0.f};
  if (i < MAXROWS) { perm[i] = -1; gates[i] = 0.f; }
  if (i < 64) hdr[i] = 0;
  if (i < 128) zp4[i] = float4{0.f, 0.f, 0.f, 0.f};
}

// ---------------- fp32 -> bf16 conversion of x, w1, w2 ----------------
__global__ void k_convert(const float4* __restrict__ x, const float4* __restrict__ w1,
                          const float4* __restrict__ w2, ushort4* __restrict__ xb,
                          ushort4* __restrict__ w1b, ushort4* __restrict__ w2b) {
  int i = blockIdx.x * blockDim.x + threadIdx.x;   // exactly 16777216 threads
  float4 v; ushort4* dst; int o;
  if (i < 8388608)       { o = i;            v = x[o];  dst = xb;  }
  else if (i < 12582912) { o = i - 8388608;  v = w1[o]; dst = w1b; }
  else                   { o = i - 12582912; v = w2[o]; dst = w2b; }
  ushort4 r; r.x = f2b(v.x); r.y = f2b(v.y); r.z = f2b(v.z); r.w = f2b(v.w);
  dst[o] = r;
}

// ---------------- histogram of expert assignments ----------------
__global__ void k_hist(const int* __restrict__ eidx, int* hdr) {
  __shared__ int lh[E_];
  if (threadIdx.x < E_) lh[threadIdx.x] = 0;
  __syncthreads();
  for (int i = blockIdx.x * blockDim.x + threadIdx.x; i < PAIRS; i += gridDim.x * blockDim.x)
    atomicAdd(&lh[eidx[i]], 1);
  __syncthreads();
  if (threadIdx.x < E_) atomicAdd(&hdr[threadIdx.x], lh[threadIdx.x]);
}

// ---------------- scan: padded row offsets + tile offsets ----------------
__global__ void k_scan(int* hdr) {
  int ro = 0, to = 0;
  hdr[16] = 0; hdr[25] = 0;
  for (int e = 0; e < E_; e++) {
    int c = hdr[e];
    int pad = ((c + 127) / 128) * 128;
    ro += pad; to += pad / 128;
    hdr[17 + e] = ro; hdr[26 + e] = to;
  }
  hdr[34] = to;
}

// ---------------- scatter pairs into per-expert segments (wave-aggregated atomics) --
__global__ void k_scatter(const int* __restrict__ eidx, const float* __restrict__ probs,
                          int* hdr, int* __restrict__ perm, float* __restrict__ gates) {
  int i = blockIdx.x * blockDim.x + threadIdx.x;   // exactly PAIRS threads
  int e = eidx[i];
  float pr = probs[i];
  int tok = i >> 1;  // K=2
  int lane = threadIdx.x & 63;
  u64 lml = (1ull << lane) - 1ull;
  for (int ex = 0; ex < E_; ex++) {
    u64 m = __ballot(e == ex);
    if (m == 0) continue;
    int cnt = __popcll(m);
    int rank = __popcll(m & lml);
    int leader = __builtin_ctzll(m);
    int base = 0;
    if (lane == leader) base = atomicAdd(&hdr[8 + ex], cnt);
    base = __shfl(base, leader, 64);
    if (e == ex) {
      int p = hdr[16 + ex] + base + rank;
      perm[p] = tok;
      gates[p] = pr;
    }
  }
}

// ---------------- MFMA GEMM (m97-style 128x128x64 tile) ----------------
using frag_ab = __attribute__((ext_vector_type(8))) short;  // 8 bf16
using frag_cd = __attribute__((ext_vector_type(4))) float;  // 4 fp32

typedef const __attribute__((address_space(1))) u32* gas_p;
typedef __attribute__((address_space(3))) u32* las_p;

__device__ __forceinline__ void glds16(const void* g, void* l) {
  __builtin_amdgcn_global_load_lds((gas_p)g, (las_p)l, 16, 0, 0);
}

// STAGE 1: h[p, :] = gates[p] * silu(xb[perm[p], :] @ w1b[e]^T)   (M x 2048, K=1024)
// STAGE 2: out[perm[p], :] += h[p, :] @ w2b[e]^T                  (M x 1024, K=2048)
template <int STAGE>
__global__ __launch_bounds__(256, 2) void k_gemm(
    const int* __restrict__ hdr, const int* __restrict__ perm,
    const float* __restrict__ gates, const u16* __restrict__ xb,
    const u16* __restrict__ w1b, const u16* __restrict__ w2b,
    u16* __restrict__ h, float* __restrict__ out, const u16* __restrict__ zp) {
  constexpr int KD = (STAGE == 1) ? 1024 : 2048;  // row length of A and of B (B^T layout)
  constexpr int NT = (STAGE == 1) ? 16 : 8;       // N / 128
  constexpr int KITERS = KD / 64;

  // XCD-aware swizzle: consecutive blockIdx round-robin across the 8 XCDs, so
  // pin all NT n-blocks of one m-tile to ONE XCD (same L2) and make them
  // consecutive in that XCD's dispatch order -> A m-tile filled into L2 once,
  // not 8x. MAXTILES=520 is divisible by 8 so coverage is exact.
  const int xcd = blockIdx.x & 7;
  const int r_ = blockIdx.x >> 3;
  const int nt_blk = r_ % NT;
  const int mt_blk = (r_ / NT) * 8 + xcd;
  if (mt_blk >= hdr[34]) return;

  // which expert owns this row-tile
  int e = 0;
  while (mt_blk >= hdr[26 + e]) e++;
  const int row0 = hdr[16 + e] + (mt_blk - hdr[25 + e]) * 128;
  const int n0 = nt_blk * 128;

  __shared__ u16 As[128 * 64];
  __shared__ u16 Bs[128 * 64];
  __shared__ u64 rb[128];

  const int tid = threadIdx.x;
  const int w = tid >> 6, lane = tid & 63;
  const int wm = w >> 1, wn = w & 1;
  const int l15 = lane & 15, l4 = lane >> 4;

  if (tid < 128) {
    u64 base;
    if (STAGE == 1) {
      int t = perm[row0 + tid];
      base = (t < 0) ? (u64)zp : (u64)(xb + (size_t)t * D_);
    } else {
      base = (u64)(h + (size_t)(row0 + tid) * F_);
    }
    rb[tid] = base;
  }
  __syncthreads();

  const u16* Bexp = (STAGE == 1) ? (w1b + (size_t)e * F_ * D_) : (w2b + (size_t)e * D_ * F_);

  // staging addresses: wave w stages rows [w*32, w*32+32) of both tiles, 4 instrs each.
  // lane covers row r = w*32 + j*8 + (lane>>3), LDS chunk c = lane&7; fetch global
  // chunk c ^ (r&7) so readers at LDS chunk g^(r&7) see logical chunk g (bank-conflict swizzle).
  const int rsub = lane >> 3;
  const u64 gsw = (u64)(((lane & 7) ^ rsub) * 16);
  u64 arb[4], brb[4];
#pragma unroll
  for (int j = 0; j < 4; j++) {
    int r = w * 32 + j * 8 + rsub;
    arb[j] = rb[r] + gsw;
    brb[j] = (u64)Bexp + (u64)(n0 + r) * (KD * 2) + gsw;
  }

  frag_cd acc[4][4];
#pragma unroll
  for (int i = 0; i < 4; i++)
#pragma unroll
    for (int j = 0; j < 4; j++) acc[i][j] = frag_cd{0.f, 0.f, 0.f, 0.f};

  for (int kit = 0; kit < KITERS; kit++) {
    const u64 koff = (u64)kit * 128;
#pragma unroll
    for (int j = 0; j < 4; j++) {
      glds16((const void*)(arb[j] + koff), (void*)(As + (w * 32 + j * 8) * 64));
      glds16((const void*)(brb[j] + koff), (void*)(Bs + (w * 32 + j * 8) * 64));
    }
    __syncthreads();
#pragma unroll
    for (int kk = 0; kk < 2; kk++) {
      frag_ab af[4], bf[4];
#pragma unroll
      for (int mt = 0; mt < 4; mt++) {
        int r = wm * 64 + mt * 16 + l15;
        int g = kk * 4 + l4;
        af[mt] = *(const frag_ab*)((const char*)As + (size_t)r * 128 + ((g ^ (l15 & 7)) * 16));
      }
#pragma unroll
      for (int nt = 0; nt < 4; nt++) {
        int r = wn * 64 + nt * 16 + l15;
        int g = kk * 4 + l4;
        bf[nt] = *(const frag_ab*)((const char*)Bs + (size_t)r * 128 + ((g ^ (l15 & 7)) * 16));
      }
#pragma unroll
      for (int mt = 0; mt < 4; mt++)
#pragma unroll
        for (int nt = 0; nt < 4; nt++)
          acc[mt][nt] = __builtin_amdgcn_mfma_f32_16x16x32_bf16(af[mt], bf[nt], acc[mt][nt], 0, 0, 0);
    }
    __syncthreads();
  }

  // epilogue. C layout: col = lane&15, row = (lane>>4)*4 + reg  [m89]
  const int col0 = n0 + wn * 64;
  if (STAGE == 1) {
#pragma unroll
    for (int mt = 0; mt < 4; mt++) {
#pragma unroll
      for (int i = 0; i < 4; i++) {
        int p = row0 + wm * 64 + mt * 16 + l4 * 4 + i;
        float gt = gates[p];  // 0 for padded rows
        u16* hrow = h + (size_t)p * F_ + col0;
#pragma unroll
        for (int nt = 0; nt < 4; nt++) {
          float v = acc[mt][nt][i];
          float s = v / (1.f + __expf(-v));  // silu
          hrow[nt * 16 + l15] = f2b(gt * s);
        }
      }
    }
  } else {
#pragma unroll
    for (int mt = 0; mt < 4; mt++) {
#pragma unroll
      for (int i = 0; i < 4; i++) {
        int p = row0 + wm * 64 + mt * 16 + l4 * 4 + i;
        int t = perm[p];
        if (t >= 0) {
          float* orow = out + (size_t)t * D_ + col0;
#pragma unroll
          for (int nt = 0; nt < 4; nt++)
            unsafeAtomicAdd(&orow[nt * 16 + l15], acc[mt][nt][i]);
        }
      }
    }
  }
}

// ---------------- correct-but-slow fallback if ws is too small ----------------
__global__ void k_naive(const float* __restrict__ x, const float* __restrict__ probs,
                        const int* __restrict__ eidx, const float* __restrict__ w1,
                        const float* __restrict__ w2, float* __restrict__ out) {
  __shared__ float xs[D_];
  __shared__ float hs[F_];
  __shared__ float os[D_];
  int t = blockIdx.x, tid = threadIdx.x;
  for (int i = tid; i < D_; i += 256) { xs[i] = x[(size_t)t * D_ + i]; os[i] = 0.f; }
  __syncthreads();
  for (int k = 0; k < K_; k++) {
    int e = eidx[t * K_ + k];
    float g = probs[t * K_ + k];
    const float* W1 = w1 + (size_t)e * F_ * D_;
    for (int f = tid; f < F_; f += 256) {
      const float* wr = W1 + (size_t)f * D_;
      float s = 0.f;
      for (int d = 0; d < D_; d++) s += xs[d] * wr[d];
      hs[f] = s / (1.f + expf(-s));
    }
    __syncthreads();
    const float* W2 = w2 + (size_t)e * D_ * F_;
    for (int dd = tid; dd < D_; dd += 256) {
      const float* wr = W2 + (size_t)dd * F_;
      float s = 0.f;
      for (int f = 0; f < F_; f++) s += hs[f] * wr[f];
      os[dd] += g * s;
    }
    __syncthreads();
  }
  for (int i = tid; i < D_; i += 256) out[(size_t)t * D_ + i] = os[i];
}

extern "C" void kernel_launch(void* const* d_in, const int* in_sizes, int n_in,
                              void* d_out, int out_size, void* d_ws, size_t ws_size,
                              hipStream_t stream) {
  const float* x = (const float*)d_in[0];
  const float* probs = (const float*)d_in[1];
  const int* eidx = (const int*)d_in[2];
  const float* w1 = (const float*)d_in[3];
  const float* w2 = (const float*)d_in[4];
  float* out = (float*)d_out;

  if (ws_size < WS_NEED) {
    k_naive<<<T_, 256, 0, stream>>>(x, probs, eidx, w1, w2, out);
    return;
  }

  char* ws = (char*)d_ws;
  int* hdr = (int*)(ws + OFF_HDR);
  float* zp = (float*)(ws + OFF_ZP);
  int* perm = (int*)(ws + OFF_PERM);
  float* gates = (float*)(ws + OFF_GATE);
  u16* xb = (u16*)(ws + OFF_XB);
  u16* w1b = (u16*)(ws + OFF_W1B);
  u16* w2b = (u16*)(ws + OFF_W2B);
  u16* h = (u16*)(ws + OFF_H);

  k_init<<<32768, 256, 0, stream>>>((float4*)out, hdr, perm, gates, (float4*)zp);
  k_convert<<<65536, 256, 0, stream>>>((const float4*)x, (const float4*)w1, (const float4*)w2,
                                       (ushort4*)xb, (ushort4*)w1b, (ushort4*)w2b);
  k_hist<<<64, 256, 0, stream>>>(eidx, hdr);
  k_scan<<<1, 1, 0, stream>>>(hdr);
  k_scatter<<<PAIRS / 256, 256, 0, stream>>>(eidx, probs, hdr, perm, gates);
  k_gemm<1><<<MAXTILES * 16, 256, 0, stream>>>(hdr, perm, gates, xb, w1b, w2b, h, out, (const u16*)zp);
  k_gemm<2><<<MAXTILES * 8, 256, 0, stream>>>(hdr, perm, gates, xb, w1b, w2b, h, out, (const u16*)zp);
}